// Round 16
// baseline (1106.249 us; speedup 1.0000x reference)
//
#include <hip/hip_runtime.h>
#include <cstdint>
#include <cstddef>

#define NPOINT 1024
#define NSAMPLE 32
#define BATCH 8
#define NPTS 4096
#define DFEAT 64
#define CIN 67
#define C1 64
#define C2 64
#define C3 128
#define BN_EPS 1e-5f

// ---------------------------------------------------------------------------
// DPP helpers. Measured notes: v_pk_*_f32 is NOT double-rate on gfx950
// (r10/r11) — all math scalar.
// ---------------------------------------------------------------------------
__device__ __forceinline__ float wave64_max_bcast(float v) {
    // values must be >= 0 (bound_ctrl zero-fill loses). Result via lane 63.
    int x;
    x = __builtin_amdgcn_update_dpp(0, __float_as_int(v), 0x111, 0xf, 0xf, true);
    v = fmaxf(v, __int_as_float(x));  // row_shr:1
    x = __builtin_amdgcn_update_dpp(0, __float_as_int(v), 0x112, 0xf, 0xf, true);
    v = fmaxf(v, __int_as_float(x));  // row_shr:2
    x = __builtin_amdgcn_update_dpp(0, __float_as_int(v), 0x114, 0xf, 0xf, true);
    v = fmaxf(v, __int_as_float(x));  // row_shr:4
    x = __builtin_amdgcn_update_dpp(0, __float_as_int(v), 0x118, 0xf, 0xf, true);
    v = fmaxf(v, __int_as_float(x));  // row_shr:8
    x = __builtin_amdgcn_update_dpp(0, __float_as_int(v), 0x142, 0xf, 0xf, true);
    v = fmaxf(v, __int_as_float(x));  // row_bcast:15
    x = __builtin_amdgcn_update_dpp(0, __float_as_int(v), 0x143, 0xf, 0xf, true);
    v = fmaxf(v, __int_as_float(x));  // row_bcast:31
    return __int_as_float(__builtin_amdgcn_readlane(__float_as_int(v), 63));
}

// max over lanes 0..7 (values replicated with period 8), broadcast from lane 7
__device__ __forceinline__ float row8_max_bcast(float v) {
    int iv = __float_as_int(v), x;
    x = __builtin_amdgcn_update_dpp(iv, iv, 0x111, 0xf, 0xf, false);  // shr1
    v = fmaxf(v, __int_as_float(x)); iv = __float_as_int(v);
    x = __builtin_amdgcn_update_dpp(iv, iv, 0x112, 0xf, 0xf, false);  // shr2
    v = fmaxf(v, __int_as_float(x)); iv = __float_as_int(v);
    x = __builtin_amdgcn_update_dpp(iv, iv, 0x114, 0xf, 0xf, false);  // shr4
    v = fmaxf(v, __int_as_float(x));
    return __int_as_float(__builtin_amdgcn_readlane(__float_as_int(v), 7));
}

// max over each 32-lane half (negatives safe). Result valid in lanes 31/63.
__device__ __forceinline__ float max32_lane31(float v) {
    int iv = __float_as_int(v), x;
    x = __builtin_amdgcn_update_dpp(iv, iv, 0x111, 0xf, 0xf, false);  // shr1
    v = fmaxf(v, __int_as_float(x)); iv = __float_as_int(v);
    x = __builtin_amdgcn_update_dpp(iv, iv, 0x112, 0xf, 0xf, false);  // shr2
    v = fmaxf(v, __int_as_float(x)); iv = __float_as_int(v);
    x = __builtin_amdgcn_update_dpp(iv, iv, 0x114, 0xf, 0xf, false);  // shr4
    v = fmaxf(v, __int_as_float(x)); iv = __float_as_int(v);
    x = __builtin_amdgcn_update_dpp(iv, iv, 0x118, 0xf, 0xf, false);  // shr8
    v = fmaxf(v, __int_as_float(x)); iv = __float_as_int(v);
    x = __builtin_amdgcn_update_dpp(iv, iv, 0x142, 0xf, 0xf, false);  // bcast15
    v = fmaxf(v, __int_as_float(x));
    return v;
}

// ---------------------------------------------------------------------------
// FPS: r8's proven scan (LDS-staged -> register-resident points, scalar
// bit-exact math) + cheap coord-carry tail (r5/r6 style, now with resident
// points): winning lane writes {x,y,z,dist} float4; one broadcast
// ds_read_b128 + 3-step DPP row-max + ballot/ctz + 3 readlanes replaces the
// 8x ds_read_b64 serial u64 reduce AND the dependent sx[last] re-reads.
// First-index tie-break preserved (lane asc, wave asc, descending rescan).
// ---------------------------------------------------------------------------
__global__ __launch_bounds__(512) void fps_kernel(const float* __restrict__ xyz,
                                                  float* __restrict__ dout) {
    const int b = blockIdx.x;
    const float* xb = xyz + (size_t)b * 3 * NPTS;
    float* ox = dout + (size_t)b * 3 * NPOINT;

    __shared__ float sx[NPTS], sy[NPTS], sz[NPTS];
    __shared__ float4 swin[2][8];

    const int t = threadIdx.x;
    const int wv = t >> 6, lane = t & 63;
    for (int j = t; j < NPTS; j += 512) {
        sx[j] = xb[j];
        sy[j] = xb[NPTS + j];
        sz[j] = xb[2 * NPTS + j];
    }
    __syncthreads();

    constexpr int PT = NPTS / 512;  // 8 points per thread, contiguous
    float px[PT], py[PT], pz[PT], dist[PT];
    const int base = t * PT;
#pragma unroll
    for (int u = 0; u < PT; ++u) {
        px[u] = sx[base + u];
        py[u] = sy[base + u];
        pz[u] = sz[base + u];
        dist[u] = 1e10f;
    }
    // opaque guard: keep scan arrays in VGPRs (no remat from LDS — r9's 9.4M
    // bank conflicts — or from global — r5/r6's slowdown)
    asm volatile("" : "+v"(px[0]), "+v"(px[1]), "+v"(px[2]), "+v"(px[3]),
                      "+v"(px[4]), "+v"(px[5]), "+v"(px[6]), "+v"(px[7]));
    asm volatile("" : "+v"(py[0]), "+v"(py[1]), "+v"(py[2]), "+v"(py[3]),
                      "+v"(py[4]), "+v"(py[5]), "+v"(py[6]), "+v"(py[7]));
    asm volatile("" : "+v"(pz[0]), "+v"(pz[1]), "+v"(pz[2]), "+v"(pz[3]),
                      "+v"(pz[4]), "+v"(pz[5]), "+v"(pz[6]), "+v"(pz[7]));

    float cx = xb[0], cy = xb[NPTS], cz = xb[2 * NPTS];  // centroid 0 = point 0
    float o0x = 0.f, o0y = 0.f, o0z = 0.f;  // centroid index t
    float o1x = 0.f, o1y = 0.f, o1z = 0.f;  // centroid index t + 512
    if (t == 0) { o0x = cx; o0y = cy; o0z = cz; }  // s = 0

    for (int s = 1; s < NPOINT; ++s) {
        float bv = 0.0f;
#pragma unroll
        for (int u = 0; u < PT; ++u) {
            float dx = __fsub_rn(px[u], cx);
            float dy = __fsub_rn(py[u], cy);
            float dz = __fsub_rn(pz[u], cz);
            float d = __fadd_rn(__fadd_rn(__fmul_rn(dx, dx), __fmul_rn(dy, dy)),
                                __fmul_rn(dz, dz));
            float nd = fminf(dist[u], d);
            dist[u] = nd;
            bv = fmaxf(bv, nd);
        }
        // wave winner: value-only DPP max, first matching lane, rescan coords
        const float wmax = wave64_max_bcast(bv);
        const unsigned long long m = __ballot(bv == wmax);
        const int fl = __builtin_ctzll(m);  // smallest lane = smallest indices
        if (lane == fl) {
            float ccx = 0.f, ccy = 0.f, ccz = 0.f;
#pragma unroll
            for (int u = PT - 1; u >= 0; --u) {  // descending -> smallest idx
                if (dist[u] == wmax) { ccx = px[u]; ccy = py[u]; ccz = pz[u]; }
            }
            swin[s & 1][wv] = make_float4(ccx, ccy, ccz, wmax);
        }
        __syncthreads();

        // cross-wave pick: 1 broadcast ds_read_b128 + DPP row-max + ctz
        const float4 e = swin[s & 1][lane & 7];
        const float gmax = row8_max_bcast(e.w);
        const unsigned long long m2 = __ballot(e.w == gmax);
        const int ws = __builtin_ctzll(m2);  // smallest wave = smallest idx
        cx = __int_as_float(__builtin_amdgcn_readlane(__float_as_int(e.x), ws));
        cy = __int_as_float(__builtin_amdgcn_readlane(__float_as_int(e.y), ws));
        cz = __int_as_float(__builtin_amdgcn_readlane(__float_as_int(e.z), ws));

        if (s == t)       { o0x = cx; o0y = cy; o0z = cz; }
        if (s == t + 512) { o1x = cx; o1y = cy; o1z = cz; }
    }

    // coalesced final writes (1024 centroids, 2 per thread)
    ox[t] = o0x;
    ox[NPOINT + t] = o0y;
    ox[2 * NPOINT + t] = o0z;
    ox[512 + t] = o1x;
    ox[NPOINT + 512 + t] = o1y;
    ox[2 * NPOINT + 512 + t] = o1z;
}

// ---------------------------------------------------------------------------
// layer1A: A[b][n][o] = sum_c W0[o][3+c] * pts[b][c][n]; output staged in LDS
// then written coalesced. Last block computes BN sc/sh constants.
// ---------------------------------------------------------------------------
__global__ __launch_bounds__(256) void layer1_pts_kernel(
    const float* __restrict__ pts, const float* __restrict__ w0,
    float* __restrict__ A,
    const float* __restrict__ b0, const float* __restrict__ g0,
    const float* __restrict__ bt0, const float* __restrict__ rm0,
    const float* __restrict__ rv0,
    const float* __restrict__ b1, const float* __restrict__ g1,
    const float* __restrict__ bt1, const float* __restrict__ rm1,
    const float* __restrict__ rv1,
    const float* __restrict__ b2, const float* __restrict__ g2,
    const float* __restrict__ bt2, const float* __restrict__ rm2,
    const float* __restrict__ rv2, float* __restrict__ bn) {
    const int t = threadIdx.x;
    if (blockIdx.x == BATCH * 64) {
        if (t < 64) {
            float sc = g0[t] * rsqrtf(rv0[t] + BN_EPS);
            bn[t] = sc;
            bn[64 + t] = fmaf(sc, b0[t] - rm0[t], bt0[t]);
        } else if (t < 128) {
            int c = t - 64;
            float sc = g1[c] * rsqrtf(rv1[c] + BN_EPS);
            bn[128 + c] = sc;
            bn[192 + c] = fmaf(sc, b1[c] - rm1[c], bt1[c]);
        } else if (t < 256) {
            int c = t - 128;
            float sc = g2[c] * rsqrtf(rv2[c] + BN_EPS);
            bn[256 + c] = sc;
            bn[384 + c] = fmaf(sc, b2[c] - rm2[c], bt2[c]);
        }
        return;
    }

    __shared__ float sp[64][65];  // [c][n]
    __shared__ float sw[64][65];  // [o][c]
    __shared__ float sA[64][65];  // [n][o] staging for coalesced write
    const int b = blockIdx.x >> 6;
    const int n0 = (blockIdx.x & 63) * 64;
    const int tn = t & 63, tq = t >> 6;  // tq in 0..3
    const float* pb = pts + (size_t)b * DFEAT * NPTS;
#pragma unroll
    for (int i = 0; i < 16; ++i) {
        int c = i * 4 + tq;
        sp[c][tn] = pb[(size_t)c * NPTS + n0 + tn];
    }
#pragma unroll
    for (int i = 0; i < 16; ++i) {
        int o = i * 4 + tq;
        sw[o][tn] = w0[o * CIN + 3 + tn];
    }
    __syncthreads();

#pragma unroll
    for (int i = 0; i < 16; ++i) {
        const int o = tq * 16 + i;
        float a0 = 0.f, a1 = 0.f, a2 = 0.f, a3 = 0.f;
#pragma unroll
        for (int c = 0; c < 64; c += 4) {
            a0 = fmaf(sw[o][c], sp[c][tn], a0);
            a1 = fmaf(sw[o][c + 1], sp[c + 1][tn], a1);
            a2 = fmaf(sw[o][c + 2], sp[c + 2][tn], a2);
            a3 = fmaf(sw[o][c + 3], sp[c + 3][tn], a3);
        }
        sA[tn][o] = (a0 + a1) + (a2 + a3);
    }
    __syncthreads();

    float* Ablk = A + ((size_t)b * NPTS + n0) * DFEAT;
#pragma unroll
    for (int j = 0; j < 16; ++j) {
        const int id = j * 256 + t;
        Ablk[id] = sA[id >> 6][id & 63];
    }
}

// ---------------------------------------------------------------------------
// Ball query: one wave per query point, parallel emission via prefix
// popcount. Bit-exact d2, first-32-by-index, pad=first.
// ---------------------------------------------------------------------------
__global__ __launch_bounds__(256) void ballquery_kernel(const float* __restrict__ xyz,
                                                        const float* __restrict__ dout,
                                                        int* __restrict__ idx) {
    const int wv = threadIdx.x >> 6, lane = threadIdx.x & 63;
    const int sg = blockIdx.x * 4 + wv;  // b*NPOINT + s
    const int b = sg / NPOINT, s = sg % NPOINT;
    const float* xb = xyz + (size_t)b * 3 * NPTS;
    const float* nx = dout + (size_t)b * 3 * NPOINT;
    const float cx = nx[s], cy = nx[NPOINT + s], cz = nx[2 * NPOINT + s];
    int* ob = idx + (size_t)sg * NSAMPLE;
    const float r2 = 0.04f;
    const unsigned long long lmask_lt = ((unsigned long long)1 << lane) - 1;

    int cnt = 0;
    int first = -1;
    for (int tch = 0; tch < NPTS / 64 && cnt < NSAMPLE; ++tch) {
        const int j = tch * 64 + lane;
        float dx = __fsub_rn(cx, xb[j]);
        float dy = __fsub_rn(cy, xb[NPTS + j]);
        float dz = __fsub_rn(cz, xb[2 * NPTS + j]);
        float d2 = __fadd_rn(__fadd_rn(__fmul_rn(dx, dx), __fmul_rn(dy, dy)),
                             __fmul_rn(dz, dz));
        const bool in = (d2 <= r2);
        const unsigned long long mask = __ballot(in);
        if (first < 0 && mask)
            first = tch * 64 + __builtin_ctzll(mask);
        if (in) {
            const int pos = cnt + __builtin_popcountll(mask & lmask_lt);
            if (pos < NSAMPLE) ob[pos] = j;
        }
        cnt += __builtin_popcountll(mask);
    }
    if (lane == 0) {
        for (int r = cnt; r < NSAMPLE; ++r) ob[r] = first;
    }
}

// ---------------------------------------------------------------------------
// Fused group + 3x conv-BN-ReLU + max over nsample. 256 thr (8 s x 32 k).
// MODE1: layer 1 = 3 xyz FMAs + precomputed A[p] row; BN via sc/sh table.
// Layer 3: k-max via DPP before BN+ReLU (monotone, sign-safe), writer k==31.
// ---------------------------------------------------------------------------
template <int MODE>
__global__ __launch_bounds__(256) void mlp_kernel(
    const float* __restrict__ xyz, const float* __restrict__ pts,
    const float* __restrict__ A, const int* __restrict__ idx,
    const float* __restrict__ dnew, const float* __restrict__ bn,
    const float* __restrict__ w0, const float* __restrict__ b0,
    const float* __restrict__ g0, const float* __restrict__ bt0,
    const float* __restrict__ rm0, const float* __restrict__ rv0,
    const float* __restrict__ w1, const float* __restrict__ b1,
    const float* __restrict__ g1, const float* __restrict__ bt1,
    const float* __restrict__ rm1, const float* __restrict__ rv1,
    const float* __restrict__ w2, const float* __restrict__ b2,
    const float* __restrict__ g2, const float* __restrict__ bt2,
    const float* __restrict__ rm2, const float* __restrict__ rv2,
    float* __restrict__ outf) {
    __shared__ float ylds[64][256];
    const int t = threadIdx.x;
    const int k = t & 31, sl = t >> 5;
    const int b = blockIdx.x >> 7;
    const int s = (blockIdx.x & 127) * 8 + sl;
    const int p = idx[((size_t)(b * NPOINT + s)) * NSAMPLE + k];

    const float* xb = xyz + (size_t)b * 3 * NPTS;
    const float* nx = dnew + (size_t)b * 3 * NPOINT;

    const float gx = xb[p] - nx[s];
    const float gy = xb[NPTS + p] - nx[NPOINT + s];
    const float gz = xb[2 * NPTS + p] - nx[2 * NPOINT + s];

    if (MODE == 1) {
        const float* Arow = A + ((size_t)b * NPTS + p) * DFEAT;
        for (int og = 0; og < C1; og += 4) {
            const float4 av = *(const float4*)(Arow + og);
#pragma unroll
            for (int u = 0; u < 4; ++u) {
                const int o = og + u;
                const float avu = (u == 0) ? av.x : (u == 1) ? av.y
                                 : (u == 2) ? av.z : av.w;
                const float* wr = w0 + o * CIN;
                float acc = fmaf(wr[0], gx,
                            fmaf(wr[1], gy, fmaf(wr[2], gz, avu)));
                float y = fmaf(bn[o], acc, bn[64 + o]);
                ylds[o][t] = fmaxf(y, 0.f);
            }
        }
    } else {
        float x[CIN];
        x[0] = gx; x[1] = gy; x[2] = gz;
        const float* pb = pts + (size_t)b * DFEAT * NPTS + p;
#pragma unroll
        for (int c = 0; c < DFEAT; ++c) x[3 + c] = pb[(size_t)c * NPTS];
        for (int o = 0; o < C1; ++o) {
            const float* wr = w0 + o * CIN;
            float a0 = 0.f, a1 = 0.f, a2 = 0.f, a3 = 0.f;
#pragma unroll
            for (int c = 0; c < 64; c += 4) {
                a0 = fmaf(wr[c], x[c], a0);
                a1 = fmaf(wr[c + 1], x[c + 1], a1);
                a2 = fmaf(wr[c + 2], x[c + 2], a2);
                a3 = fmaf(wr[c + 3], x[c + 3], a3);
            }
            a0 = fmaf(wr[64], x[64], a0);
            a1 = fmaf(wr[65], x[65], a1);
            a2 = fmaf(wr[66], x[66], a2);
            float acc = (a0 + a1) + (a2 + a3);
            float sc = g0[o] * rsqrtf(rv0[o] + BN_EPS);
            float y = fmaf(sc, acc + b0[o] - rm0[o], bt0[o]);
            ylds[o][t] = fmaxf(y, 0.f);
        }
    }
    __syncthreads();
    float x1[C1];
#pragma unroll
    for (int c = 0; c < C1; ++c) x1[c] = ylds[c][t];
    __syncthreads();

    // layer 2: 64 -> 64
    for (int o = 0; o < C2; ++o) {
        const float* wr = w1 + o * C1;
        float a0 = 0.f, a1 = 0.f, a2 = 0.f, a3 = 0.f;
#pragma unroll
        for (int c = 0; c < C1; c += 4) {
            a0 = fmaf(wr[c], x1[c], a0);
            a1 = fmaf(wr[c + 1], x1[c + 1], a1);
            a2 = fmaf(wr[c + 2], x1[c + 2], a2);
            a3 = fmaf(wr[c + 3], x1[c + 3], a3);
        }
        float acc = (a0 + a1) + (a2 + a3);
        float y;
        if (MODE == 1) {
            y = fmaf(bn[128 + o], acc, bn[192 + o]);
        } else {
            float sc = g1[o] * rsqrtf(rv1[o] + BN_EPS);
            y = fmaf(sc, acc + b1[o] - rm1[o], bt1[o]);
        }
        ylds[o][t] = fmaxf(y, 0.f);
    }
    __syncthreads();
    float x2[C2];
#pragma unroll
    for (int c = 0; c < C2; ++c) x2[c] = ylds[c][t];

    // layer 3: 64 -> 128; k-max (DPP) before BN+ReLU
    float* ob = outf + (size_t)b * C3 * NPOINT;
    for (int o = 0; o < C3; ++o) {
        const float* wr = w2 + o * C2;
        float a0 = 0.f, a1 = 0.f, a2 = 0.f, a3 = 0.f;
#pragma unroll
        for (int c = 0; c < C2; c += 4) {
            a0 = fmaf(wr[c], x2[c], a0);
            a1 = fmaf(wr[c + 1], x2[c + 1], a1);
            a2 = fmaf(wr[c + 2], x2[c + 2], a2);
            a3 = fmaf(wr[c + 3], x2[c + 3], a3);
        }
        float acc = (a0 + a1) + (a2 + a3);
        float sc, sh;
        if (MODE == 1) {
            sc = bn[256 + o];
            sh = bn[384 + o];
        } else {
            sc = g2[o] * rsqrtf(rv2[o] + BN_EPS);
            sh = fmaf(sc, b2[o] - rm2[o], bt2[o]);
        }
        float key = (sc >= 0.f) ? acc : -acc;
        float mred = max32_lane31(key);
        if (k == 31) {
            float asel = (sc >= 0.f) ? mred : -mred;
            float y = fmaf(sc, asel, sh);
            ob[(size_t)o * NPOINT + s] = fmaxf(y, 0.f);
        }
    }
}

// ---------------------------------------------------------------------------
extern "C" void kernel_launch(void* const* d_in, const int* in_sizes, int n_in,
                              void* d_out, int out_size, void* d_ws, size_t ws_size,
                              hipStream_t stream) {
    const float* xyz = (const float*)d_in[0];
    const float* pts = (const float*)d_in[1];
    const float* w0 = (const float*)d_in[2];
    const float* b0 = (const float*)d_in[3];
    const float* g0 = (const float*)d_in[4];
    const float* bt0 = (const float*)d_in[5];
    const float* rm0 = (const float*)d_in[6];
    const float* rv0 = (const float*)d_in[7];
    const float* w1 = (const float*)d_in[8];
    const float* b1 = (const float*)d_in[9];
    const float* g1 = (const float*)d_in[10];
    const float* bt1 = (const float*)d_in[11];
    const float* rm1 = (const float*)d_in[12];
    const float* rv1 = (const float*)d_in[13];
    const float* w2 = (const float*)d_in[14];
    const float* b2 = (const float*)d_in[15];
    const float* g2 = (const float*)d_in[16];
    const float* bt2 = (const float*)d_in[17];
    const float* rm2 = (const float*)d_in[18];
    const float* rv2 = (const float*)d_in[19];

    float* out = (float*)d_out;
    float* outf = out + (size_t)BATCH * 3 * NPOINT;

    const size_t idx_bytes = (size_t)BATCH * NPOINT * NSAMPLE * sizeof(int);  // 1 MB
    const size_t idx_pad = (idx_bytes + 255) & ~(size_t)255;
    const size_t A_bytes = (size_t)BATCH * NPTS * DFEAT * sizeof(float);      // 8 MB
    const size_t bn_bytes = 640 * sizeof(float);
    int* idx = (int*)d_ws;
    float* A = (float*)((char*)d_ws + idx_pad);
    float* bn = (float*)((char*)d_ws + idx_pad + A_bytes);
    const bool useA = ws_size >= idx_pad + A_bytes + bn_bytes;

    fps_kernel<<<BATCH, 512, 0, stream>>>(xyz, out);
    if (useA) {
        layer1_pts_kernel<<<BATCH * 64 + 1, 256, 0, stream>>>(
            pts, w0, A, b0, g0, bt0, rm0, rv0, b1, g1, bt1, rm1, rv1,
            b2, g2, bt2, rm2, rv2, bn);
    }
    ballquery_kernel<<<BATCH * NPOINT / 4, 256, 0, stream>>>(xyz, out, idx);
    if (useA) {
        mlp_kernel<1><<<BATCH * NPOINT / 8, 256, 0, stream>>>(
            xyz, pts, A, idx, out, bn, w0, b0, g0, bt0, rm0, rv0, w1, b1, g1,
            bt1, rm1, rv1, w2, b2, g2, bt2, rm2, rv2, outf);
    } else {
        mlp_kernel<0><<<BATCH * NPOINT / 8, 256, 0, stream>>>(
            xyz, pts, A, idx, out, bn, w0, b0, g0, bt0, rm0, rv0, w1, b1, g1,
            bt1, rm1, rv1, w2, b2, g2, bt2, rm2, rv2, outf);
    }
}

// Round 17
// 960.587 us; speedup vs baseline: 1.1516x; 1.1516x over previous
//
#include <hip/hip_runtime.h>
#include <cstdint>
#include <cstddef>

#define NPOINT 1024
#define NSAMPLE 32
#define BATCH 8
#define NPTS 4096
#define DFEAT 64
#define CIN 67
#define C1 64
#define C2 64
#define C3 128
#define BN_EPS 1e-5f

#define NBQ (BATCH * NPOINT / 4)   // 2048 ball-query blocks
#define NL1 (BATCH * 64)           // 512 layer1A tiles

// ---------------------------------------------------------------------------
// DPP helpers. Measured notes: v_pk_*_f32 is NOT double-rate on gfx950
// (r10/r11); pipelined LDS reduce beats serial hazard-chain tails (r6/r16).
// ---------------------------------------------------------------------------
__device__ __forceinline__ float wave64_max_bcast(float v) {
    // values must be >= 0 (bound_ctrl zero-fill loses). Result via lane 63.
    int x;
    x = __builtin_amdgcn_update_dpp(0, __float_as_int(v), 0x111, 0xf, 0xf, true);
    v = fmaxf(v, __int_as_float(x));  // row_shr:1
    x = __builtin_amdgcn_update_dpp(0, __float_as_int(v), 0x112, 0xf, 0xf, true);
    v = fmaxf(v, __int_as_float(x));  // row_shr:2
    x = __builtin_amdgcn_update_dpp(0, __float_as_int(v), 0x114, 0xf, 0xf, true);
    v = fmaxf(v, __int_as_float(x));  // row_shr:4
    x = __builtin_amdgcn_update_dpp(0, __float_as_int(v), 0x118, 0xf, 0xf, true);
    v = fmaxf(v, __int_as_float(x));  // row_shr:8
    x = __builtin_amdgcn_update_dpp(0, __float_as_int(v), 0x142, 0xf, 0xf, true);
    v = fmaxf(v, __int_as_float(x));  // row_bcast:15
    x = __builtin_amdgcn_update_dpp(0, __float_as_int(v), 0x143, 0xf, 0xf, true);
    v = fmaxf(v, __int_as_float(x));  // row_bcast:31
    return __int_as_float(__builtin_amdgcn_readlane(__float_as_int(v), 63));
}

// max over each 32-lane half (negatives safe). Result valid in lanes 31/63.
__device__ __forceinline__ float max32_lane31(float v) {
    int iv = __float_as_int(v), x;
    x = __builtin_amdgcn_update_dpp(iv, iv, 0x111, 0xf, 0xf, false);  // shr1
    v = fmaxf(v, __int_as_float(x)); iv = __float_as_int(v);
    x = __builtin_amdgcn_update_dpp(iv, iv, 0x112, 0xf, 0xf, false);  // shr2
    v = fmaxf(v, __int_as_float(x)); iv = __float_as_int(v);
    x = __builtin_amdgcn_update_dpp(iv, iv, 0x114, 0xf, 0xf, false);  // shr4
    v = fmaxf(v, __int_as_float(x)); iv = __float_as_int(v);
    x = __builtin_amdgcn_update_dpp(iv, iv, 0x118, 0xf, 0xf, false);  // shr8
    v = fmaxf(v, __int_as_float(x)); iv = __float_as_int(v);
    x = __builtin_amdgcn_update_dpp(iv, iv, 0x142, 0xf, 0xf, false);  // bcast15
    v = fmaxf(v, __int_as_float(x));
    return v;
}

// ---------------------------------------------------------------------------
// FPS: byte-identical to r8/r15 champion (644 us). DO NOT TOUCH — 10
// variants tried (pk scan, cheap tails, merged aux, thread counts); only
// the in-loop-store removal (r8) ever won.
// ---------------------------------------------------------------------------
__global__ __launch_bounds__(512) void fps_kernel(const float* __restrict__ xyz,
                                                  float* __restrict__ dout) {
    const int b = blockIdx.x;
    const float* xb = xyz + (size_t)b * 3 * NPTS;
    float* ox = dout + (size_t)b * 3 * NPOINT;

    __shared__ float sx[NPTS], sy[NPTS], sz[NPTS];
    __shared__ unsigned long long redk[2][8];

    const int t = threadIdx.x;
    const int wv = t >> 6;
    for (int j = t; j < NPTS; j += 512) {
        sx[j] = xb[j];
        sy[j] = xb[NPTS + j];
        sz[j] = xb[2 * NPTS + j];
    }
    __syncthreads();

    constexpr int PT = NPTS / 512;  // 8 points per thread, contiguous
    float px[PT], py[PT], pz[PT], dist[PT];
    const int base = t * PT;
#pragma unroll
    for (int u = 0; u < PT; ++u) {
        px[u] = sx[base + u];
        py[u] = sy[base + u];
        pz[u] = sz[base + u];
        dist[u] = 1e10f;
    }

    int last = 0;
    float o0x = 0.f, o0y = 0.f, o0z = 0.f;  // centroid index t
    float o1x = 0.f, o1y = 0.f, o1z = 0.f;  // centroid index t + 512

    for (int s = 1; s < NPOINT; ++s) {
        const float cx = sx[last], cy = sy[last], cz = sz[last];
        if (s - 1 == t)       { o0x = cx; o0y = cy; o0z = cz; }
        if (s - 1 == t + 512) { o1x = cx; o1y = cy; o1z = cz; }

        float bv = 0.0f;
#pragma unroll
        for (int u = 0; u < PT; ++u) {
            float dx = __fsub_rn(px[u], cx);
            float dy = __fsub_rn(py[u], cy);
            float dz = __fsub_rn(pz[u], cz);
            float d = __fadd_rn(__fadd_rn(__fmul_rn(dx, dx), __fmul_rn(dy, dy)),
                                __fmul_rn(dz, dz));
            float nd = fminf(dist[u], d);
            dist[u] = nd;
            bv = fmaxf(bv, nd);
        }
        const float wmax = wave64_max_bcast(bv);
        int li = 0;
        if (bv == wmax) {
#pragma unroll
            for (int u = PT - 1; u >= 0; --u)
                if (dist[u] == wmax) li = base + u;  // descending -> smallest
        }
        const unsigned long long m = __ballot(bv == wmax);
        const int fl = __builtin_ctzll(m);
        const int wbi = __builtin_amdgcn_readlane(li, fl);

        if ((t & 63) == 0) {
            redk[s & 1][wv] =
                ((unsigned long long)__float_as_uint(wmax) << 32) |
                (unsigned)(0xFFFFFFFFu - (unsigned)wbi);
        }
        __syncthreads();
        unsigned long long gk = redk[s & 1][0];
#pragma unroll
        for (int w = 1; w < 8; ++w) {
            unsigned long long k2 = redk[s & 1][w];
            if (k2 > gk) gk = k2;
        }
        last = (int)(0xFFFFFFFFu - (unsigned)(gk & 0xFFFFFFFFull));
    }

    {
        const float cx = sx[last], cy = sy[last], cz = sz[last];
        if (t == 511) { o1x = cx; o1y = cy; o1z = cz; }  // 1023 == 511 + 512
    }

    ox[t] = o0x;
    ox[NPOINT + t] = o0y;
    ox[2 * NPOINT + t] = o0z;
    ox[512 + t] = o1x;
    ox[NPOINT + 512 + t] = o1y;
    ox[2 * NPOINT + 512 + t] = o1z;
}

// ---------------------------------------------------------------------------
// Merged epilogue-1 dispatch:
//   blocks [0, NBQ)          : ball query (4 waves x 1 query), bit-exact,
//                              parallel emission via prefix popcount.
//   blocks [NBQ, NBQ+NL1)    : layer1A tile — A[b][n][o] = sum_c
//                              W0[o][3+c]*pts[b][c][n], registers then
//                              coalesced write (sA reuses sw storage).
//   block  NBQ+NL1           : BN sc/sh constants.
// layer1A/bn depend on nothing; bq depends only on fps output — all ready.
// ---------------------------------------------------------------------------
__global__ __launch_bounds__(256) void epi1_kernel(
    const float* __restrict__ xyz, const float* __restrict__ dout,
    int* __restrict__ idx,
    const float* __restrict__ pts, const float* __restrict__ w0,
    float* __restrict__ A,
    const float* __restrict__ b0, const float* __restrict__ g0,
    const float* __restrict__ bt0, const float* __restrict__ rm0,
    const float* __restrict__ rv0,
    const float* __restrict__ b1, const float* __restrict__ g1,
    const float* __restrict__ bt1, const float* __restrict__ rm1,
    const float* __restrict__ rv1,
    const float* __restrict__ b2, const float* __restrict__ g2,
    const float* __restrict__ bt2, const float* __restrict__ rm2,
    const float* __restrict__ rv2, float* __restrict__ bn) {
    __shared__ float sp[64][65];   // [c][n]
    __shared__ float swA[64][65];  // [o][c] during compute, then [n][o]
    const int t = threadIdx.x;
    const int bid = blockIdx.x;

    if (bid < NBQ) {
        // ---------------- ball query ----------------
        const int wv = t >> 6, lane = t & 63;
        const int sg = bid * 4 + wv;  // b*NPOINT + s
        const int b = sg >> 10, s = sg & (NPOINT - 1);
        const float* xb = xyz + (size_t)b * 3 * NPTS;
        const float* nx = dout + (size_t)b * 3 * NPOINT;
        const float cx = nx[s], cy = nx[NPOINT + s], cz = nx[2 * NPOINT + s];
        int* ob = idx + (size_t)sg * NSAMPLE;
        const float r2 = 0.04f;
        const unsigned long long lmask_lt = ((unsigned long long)1 << lane) - 1;

        int cnt = 0;
        int first = -1;
        for (int tch = 0; tch < NPTS / 64 && cnt < NSAMPLE; ++tch) {
            const int j = tch * 64 + lane;
            float dx = __fsub_rn(cx, xb[j]);
            float dy = __fsub_rn(cy, xb[NPTS + j]);
            float dz = __fsub_rn(cz, xb[2 * NPTS + j]);
            float d2 = __fadd_rn(__fadd_rn(__fmul_rn(dx, dx), __fmul_rn(dy, dy)),
                                 __fmul_rn(dz, dz));
            const bool in = (d2 <= r2);
            const unsigned long long mask = __ballot(in);
            if (first < 0 && mask)
                first = tch * 64 + __builtin_ctzll(mask);
            if (in) {
                const int pos = cnt + __builtin_popcountll(mask & lmask_lt);
                if (pos < NSAMPLE) ob[pos] = j;
            }
            cnt += __builtin_popcountll(mask);
        }
        if (lane == 0) {
            for (int r = cnt; r < NSAMPLE; ++r) ob[r] = first;
        }
        return;
    }

    if (bid == NBQ + NL1) {
        // ---------------- BN constants: y = sc*acc + sh ----------------
        if (t < 64) {
            float sc = g0[t] * rsqrtf(rv0[t] + BN_EPS);
            bn[t] = sc;
            bn[64 + t] = fmaf(sc, b0[t] - rm0[t], bt0[t]);
        } else if (t < 128) {
            int c = t - 64;
            float sc = g1[c] * rsqrtf(rv1[c] + BN_EPS);
            bn[128 + c] = sc;
            bn[192 + c] = fmaf(sc, b1[c] - rm1[c], bt1[c]);
        } else if (t < 256) {
            int c = t - 128;
            float sc = g2[c] * rsqrtf(rv2[c] + BN_EPS);
            bn[256 + c] = sc;
            bn[384 + c] = fmaf(sc, b2[c] - rm2[c], bt2[c]);
        }
        return;
    }

    // ---------------- layer1A tile ----------------
    const int tb = bid - NBQ;
    const int b = tb >> 6;
    const int n0 = (tb & 63) * 64;
    const int tn = t & 63, tq = t >> 6;  // tq in 0..3
    const float* pb = pts + (size_t)b * DFEAT * NPTS;
#pragma unroll
    for (int i = 0; i < 16; ++i) {
        int c = i * 4 + tq;
        sp[c][tn] = pb[(size_t)c * NPTS + n0 + tn];
    }
#pragma unroll
    for (int i = 0; i < 16; ++i) {
        int o = i * 4 + tq;
        swA[o][tn] = w0[o * CIN + 3 + tn];
    }
    __syncthreads();

    float racc[16];
#pragma unroll
    for (int i = 0; i < 16; ++i) {
        const int o = tq * 16 + i;
        float a0 = 0.f, a1 = 0.f, a2 = 0.f, a3 = 0.f;
#pragma unroll
        for (int c = 0; c < 64; c += 4) {
            a0 = fmaf(swA[o][c], sp[c][tn], a0);
            a1 = fmaf(swA[o][c + 1], sp[c + 1][tn], a1);
            a2 = fmaf(swA[o][c + 2], sp[c + 2][tn], a2);
            a3 = fmaf(swA[o][c + 3], sp[c + 3][tn], a3);
        }
        racc[i] = (a0 + a1) + (a2 + a3);
    }
    __syncthreads();  // all reads of swA done; reuse as sA[n][o]

#pragma unroll
    for (int i = 0; i < 16; ++i) {
        const int o = tq * 16 + i;
        swA[tn][o] = racc[i];
    }
    __syncthreads();

    float* Ablk = A + ((size_t)b * NPTS + n0) * DFEAT;
#pragma unroll
    for (int j = 0; j < 16; ++j) {
        const int id = j * 256 + t;
        Ablk[id] = swA[id >> 6][id & 63];
    }
}

// ---------------------------------------------------------------------------
// Fallback standalone ball query (used only when ws too small for A).
// ---------------------------------------------------------------------------
__global__ __launch_bounds__(256) void ballquery_kernel(const float* __restrict__ xyz,
                                                        const float* __restrict__ dout,
                                                        int* __restrict__ idx) {
    const int wv = threadIdx.x >> 6, lane = threadIdx.x & 63;
    const int sg = blockIdx.x * 4 + wv;
    const int b = sg / NPOINT, s = sg % NPOINT;
    const float* xb = xyz + (size_t)b * 3 * NPTS;
    const float* nx = dout + (size_t)b * 3 * NPOINT;
    const float cx = nx[s], cy = nx[NPOINT + s], cz = nx[2 * NPOINT + s];
    int* ob = idx + (size_t)sg * NSAMPLE;
    const float r2 = 0.04f;
    const unsigned long long lmask_lt = ((unsigned long long)1 << lane) - 1;

    int cnt = 0;
    int first = -1;
    for (int tch = 0; tch < NPTS / 64 && cnt < NSAMPLE; ++tch) {
        const int j = tch * 64 + lane;
        float dx = __fsub_rn(cx, xb[j]);
        float dy = __fsub_rn(cy, xb[NPTS + j]);
        float dz = __fsub_rn(cz, xb[2 * NPTS + j]);
        float d2 = __fadd_rn(__fadd_rn(__fmul_rn(dx, dx), __fmul_rn(dy, dy)),
                             __fmul_rn(dz, dz));
        const bool in = (d2 <= r2);
        const unsigned long long mask = __ballot(in);
        if (first < 0 && mask)
            first = tch * 64 + __builtin_ctzll(mask);
        if (in) {
            const int pos = cnt + __builtin_popcountll(mask & lmask_lt);
            if (pos < NSAMPLE) ob[pos] = j;
        }
        cnt += __builtin_popcountll(mask);
    }
    if (lane == 0) {
        for (int r = cnt; r < NSAMPLE; ++r) ob[r] = first;
    }
}

// ---------------------------------------------------------------------------
// Fused group + 3x conv-BN-ReLU + max over nsample. 256 thr (8 s x 32 k).
// Byte-identical to r15's mlp. MODE1: layer 1 = 3 xyz FMAs + A[p] row; BN
// via sc/sh table. Layer 3: k-max via DPP before BN+ReLU, writer k==31.
// ---------------------------------------------------------------------------
template <int MODE>
__global__ __launch_bounds__(256) void mlp_kernel(
    const float* __restrict__ xyz, const float* __restrict__ pts,
    const float* __restrict__ A, const int* __restrict__ idx,
    const float* __restrict__ dnew, const float* __restrict__ bn,
    const float* __restrict__ w0, const float* __restrict__ b0,
    const float* __restrict__ g0, const float* __restrict__ bt0,
    const float* __restrict__ rm0, const float* __restrict__ rv0,
    const float* __restrict__ w1, const float* __restrict__ b1,
    const float* __restrict__ g1, const float* __restrict__ bt1,
    const float* __restrict__ rm1, const float* __restrict__ rv1,
    const float* __restrict__ w2, const float* __restrict__ b2,
    const float* __restrict__ g2, const float* __restrict__ bt2,
    const float* __restrict__ rm2, const float* __restrict__ rv2,
    float* __restrict__ outf) {
    __shared__ float ylds[64][256];
    const int t = threadIdx.x;
    const int k = t & 31, sl = t >> 5;
    const int b = blockIdx.x >> 7;
    const int s = (blockIdx.x & 127) * 8 + sl;
    const int p = idx[((size_t)(b * NPOINT + s)) * NSAMPLE + k];

    const float* xb = xyz + (size_t)b * 3 * NPTS;
    const float* nx = dnew + (size_t)b * 3 * NPOINT;

    const float gx = xb[p] - nx[s];
    const float gy = xb[NPTS + p] - nx[NPOINT + s];
    const float gz = xb[2 * NPTS + p] - nx[2 * NPOINT + s];

    if (MODE == 1) {
        const float* Arow = A + ((size_t)b * NPTS + p) * DFEAT;
        for (int og = 0; og < C1; og += 4) {
            const float4 av = *(const float4*)(Arow + og);
#pragma unroll
            for (int u = 0; u < 4; ++u) {
                const int o = og + u;
                const float avu = (u == 0) ? av.x : (u == 1) ? av.y
                                 : (u == 2) ? av.z : av.w;
                const float* wr = w0 + o * CIN;
                float acc = fmaf(wr[0], gx,
                            fmaf(wr[1], gy, fmaf(wr[2], gz, avu)));
                float y = fmaf(bn[o], acc, bn[64 + o]);
                ylds[o][t] = fmaxf(y, 0.f);
            }
        }
    } else {
        float x[CIN];
        x[0] = gx; x[1] = gy; x[2] = gz;
        const float* pb = pts + (size_t)b * DFEAT * NPTS + p;
#pragma unroll
        for (int c = 0; c < DFEAT; ++c) x[3 + c] = pb[(size_t)c * NPTS];
        for (int o = 0; o < C1; ++o) {
            const float* wr = w0 + o * CIN;
            float a0 = 0.f, a1 = 0.f, a2 = 0.f, a3 = 0.f;
#pragma unroll
            for (int c = 0; c < 64; c += 4) {
                a0 = fmaf(wr[c], x[c], a0);
                a1 = fmaf(wr[c + 1], x[c + 1], a1);
                a2 = fmaf(wr[c + 2], x[c + 2], a2);
                a3 = fmaf(wr[c + 3], x[c + 3], a3);
            }
            a0 = fmaf(wr[64], x[64], a0);
            a1 = fmaf(wr[65], x[65], a1);
            a2 = fmaf(wr[66], x[66], a2);
            float acc = (a0 + a1) + (a2 + a3);
            float sc = g0[o] * rsqrtf(rv0[o] + BN_EPS);
            float y = fmaf(sc, acc + b0[o] - rm0[o], bt0[o]);
            ylds[o][t] = fmaxf(y, 0.f);
        }
    }
    __syncthreads();
    float x1[C1];
#pragma unroll
    for (int c = 0; c < C1; ++c) x1[c] = ylds[c][t];
    __syncthreads();

    // layer 2: 64 -> 64
    for (int o = 0; o < C2; ++o) {
        const float* wr = w1 + o * C1;
        float a0 = 0.f, a1 = 0.f, a2 = 0.f, a3 = 0.f;
#pragma unroll
        for (int c = 0; c < C1; c += 4) {
            a0 = fmaf(wr[c], x1[c], a0);
            a1 = fmaf(wr[c + 1], x1[c + 1], a1);
            a2 = fmaf(wr[c + 2], x1[c + 2], a2);
            a3 = fmaf(wr[c + 3], x1[c + 3], a3);
        }
        float acc = (a0 + a1) + (a2 + a3);
        float y;
        if (MODE == 1) {
            y = fmaf(bn[128 + o], acc, bn[192 + o]);
        } else {
            float sc = g1[o] * rsqrtf(rv1[o] + BN_EPS);
            y = fmaf(sc, acc + b1[o] - rm1[o], bt1[o]);
        }
        ylds[o][t] = fmaxf(y, 0.f);
    }
    __syncthreads();
    float x2[C2];
#pragma unroll
    for (int c = 0; c < C2; ++c) x2[c] = ylds[c][t];

    // layer 3: 64 -> 128; k-max (DPP) before BN+ReLU
    float* ob = outf + (size_t)b * C3 * NPOINT;
    for (int o = 0; o < C3; ++o) {
        const float* wr = w2 + o * C2;
        float a0 = 0.f, a1 = 0.f, a2 = 0.f, a3 = 0.f;
#pragma unroll
        for (int c = 0; c < C2; c += 4) {
            a0 = fmaf(wr[c], x2[c], a0);
            a1 = fmaf(wr[c + 1], x2[c + 1], a1);
            a2 = fmaf(wr[c + 2], x2[c + 2], a2);
            a3 = fmaf(wr[c + 3], x2[c + 3], a3);
        }
        float acc = (a0 + a1) + (a2 + a3);
        float sc, sh;
        if (MODE == 1) {
            sc = bn[256 + o];
            sh = bn[384 + o];
        } else {
            sc = g2[o] * rsqrtf(rv2[o] + BN_EPS);
            sh = fmaf(sc, b2[o] - rm2[o], bt2[o]);
        }
        float key = (sc >= 0.f) ? acc : -acc;
        float mred = max32_lane31(key);
        if (k == 31) {
            float asel = (sc >= 0.f) ? mred : -mred;
            float y = fmaf(sc, asel, sh);
            ob[(size_t)o * NPOINT + s] = fmaxf(y, 0.f);
        }
    }
}

// ---------------------------------------------------------------------------
extern "C" void kernel_launch(void* const* d_in, const int* in_sizes, int n_in,
                              void* d_out, int out_size, void* d_ws, size_t ws_size,
                              hipStream_t stream) {
    const float* xyz = (const float*)d_in[0];
    const float* pts = (const float*)d_in[1];
    const float* w0 = (const float*)d_in[2];
    const float* b0 = (const float*)d_in[3];
    const float* g0 = (const float*)d_in[4];
    const float* bt0 = (const float*)d_in[5];
    const float* rm0 = (const float*)d_in[6];
    const float* rv0 = (const float*)d_in[7];
    const float* w1 = (const float*)d_in[8];
    const float* b1 = (const float*)d_in[9];
    const float* g1 = (const float*)d_in[10];
    const float* bt1 = (const float*)d_in[11];
    const float* rm1 = (const float*)d_in[12];
    const float* rv1 = (const float*)d_in[13];
    const float* w2 = (const float*)d_in[14];
    const float* b2 = (const float*)d_in[15];
    const float* g2 = (const float*)d_in[16];
    const float* bt2 = (const float*)d_in[17];
    const float* rm2 = (const float*)d_in[18];
    const float* rv2 = (const float*)d_in[19];

    float* out = (float*)d_out;
    float* outf = out + (size_t)BATCH * 3 * NPOINT;

    const size_t idx_bytes = (size_t)BATCH * NPOINT * NSAMPLE * sizeof(int);  // 1 MB
    const size_t idx_pad = (idx_bytes + 255) & ~(size_t)255;
    const size_t A_bytes = (size_t)BATCH * NPTS * DFEAT * sizeof(float);      // 8 MB
    const size_t bn_bytes = 640 * sizeof(float);
    int* idx = (int*)d_ws;
    float* A = (float*)((char*)d_ws + idx_pad);
    float* bn = (float*)((char*)d_ws + idx_pad + A_bytes);
    const bool useA = ws_size >= idx_pad + A_bytes + bn_bytes;

    fps_kernel<<<BATCH, 512, 0, stream>>>(xyz, out);
    if (useA) {
        epi1_kernel<<<NBQ + NL1 + 1, 256, 0, stream>>>(
            xyz, out, idx, pts, w0, A, b0, g0, bt0, rm0, rv0,
            b1, g1, bt1, rm1, rv1, b2, g2, bt2, rm2, rv2, bn);
        mlp_kernel<1><<<BATCH * NPOINT / 8, 256, 0, stream>>>(
            xyz, pts, A, idx, out, bn, w0, b0, g0, bt0, rm0, rv0, w1, b1, g1,
            bt1, rm1, rv1, w2, b2, g2, bt2, rm2, rv2, outf);
    } else {
        ballquery_kernel<<<NBQ, 256, 0, stream>>>(xyz, out, idx);
        mlp_kernel<0><<<BATCH * NPOINT / 8, 256, 0, stream>>>(
            xyz, pts, A, idx, out, bn, w0, b0, g0, bt0, rm0, rv0, w1, b1, g1,
            bt1, rm1, rv1, w2, b2, g2, bt2, rm2, rv2, outf);
    }
}

// Round 18
// 933.907 us; speedup vs baseline: 1.1845x; 1.0286x over previous
//
#include <hip/hip_runtime.h>
#include <cstdint>
#include <cstddef>

#define NPOINT 1024
#define NSAMPLE 32
#define BATCH 8
#define NPTS 4096
#define DFEAT 64
#define CIN 67
#define C1 64
#define C2 64
#define C3 128
#define BN_EPS 1e-5f

// ---------------------------------------------------------------------------
// DPP helpers. Measured notes: v_pk_*_f32 is NOT double-rate on gfx950
// (r10/r11); pipelined LDS reduce beats serial hazard-chain tails (r6/r16);
// merged dispatches inherit max resource footprint across branches (r14/r17)
// — keep kernels separate unless footprints match.
// ---------------------------------------------------------------------------
__device__ __forceinline__ float wave64_max_bcast(float v) {
    // values must be >= 0 (bound_ctrl zero-fill loses). Result via lane 63.
    int x;
    x = __builtin_amdgcn_update_dpp(0, __float_as_int(v), 0x111, 0xf, 0xf, true);
    v = fmaxf(v, __int_as_float(x));  // row_shr:1
    x = __builtin_amdgcn_update_dpp(0, __float_as_int(v), 0x112, 0xf, 0xf, true);
    v = fmaxf(v, __int_as_float(x));  // row_shr:2
    x = __builtin_amdgcn_update_dpp(0, __float_as_int(v), 0x114, 0xf, 0xf, true);
    v = fmaxf(v, __int_as_float(x));  // row_shr:4
    x = __builtin_amdgcn_update_dpp(0, __float_as_int(v), 0x118, 0xf, 0xf, true);
    v = fmaxf(v, __int_as_float(x));  // row_shr:8
    x = __builtin_amdgcn_update_dpp(0, __float_as_int(v), 0x142, 0xf, 0xf, true);
    v = fmaxf(v, __int_as_float(x));  // row_bcast:15
    x = __builtin_amdgcn_update_dpp(0, __float_as_int(v), 0x143, 0xf, 0xf, true);
    v = fmaxf(v, __int_as_float(x));  // row_bcast:31
    return __int_as_float(__builtin_amdgcn_readlane(__float_as_int(v), 63));
}

// max over each 32-lane half (negatives safe). Result valid in lanes 31/63.
__device__ __forceinline__ float max32_lane31(float v) {
    int iv = __float_as_int(v), x;
    x = __builtin_amdgcn_update_dpp(iv, iv, 0x111, 0xf, 0xf, false);  // shr1
    v = fmaxf(v, __int_as_float(x)); iv = __float_as_int(v);
    x = __builtin_amdgcn_update_dpp(iv, iv, 0x112, 0xf, 0xf, false);  // shr2
    v = fmaxf(v, __int_as_float(x)); iv = __float_as_int(v);
    x = __builtin_amdgcn_update_dpp(iv, iv, 0x114, 0xf, 0xf, false);  // shr4
    v = fmaxf(v, __int_as_float(x)); iv = __float_as_int(v);
    x = __builtin_amdgcn_update_dpp(iv, iv, 0x118, 0xf, 0xf, false);  // shr8
    v = fmaxf(v, __int_as_float(x)); iv = __float_as_int(v);
    x = __builtin_amdgcn_update_dpp(iv, iv, 0x142, 0xf, 0xf, false);  // bcast15
    v = fmaxf(v, __int_as_float(x));
    return v;
}

// ---------------------------------------------------------------------------
// FPS: byte-identical to r8/r15 champion (644 us). DO NOT TOUCH.
// ---------------------------------------------------------------------------
__global__ __launch_bounds__(512) void fps_kernel(const float* __restrict__ xyz,
                                                  float* __restrict__ dout) {
    const int b = blockIdx.x;
    const float* xb = xyz + (size_t)b * 3 * NPTS;
    float* ox = dout + (size_t)b * 3 * NPOINT;

    __shared__ float sx[NPTS], sy[NPTS], sz[NPTS];
    __shared__ unsigned long long redk[2][8];

    const int t = threadIdx.x;
    const int wv = t >> 6;
    for (int j = t; j < NPTS; j += 512) {
        sx[j] = xb[j];
        sy[j] = xb[NPTS + j];
        sz[j] = xb[2 * NPTS + j];
    }
    __syncthreads();

    constexpr int PT = NPTS / 512;  // 8 points per thread, contiguous
    float px[PT], py[PT], pz[PT], dist[PT];
    const int base = t * PT;
#pragma unroll
    for (int u = 0; u < PT; ++u) {
        px[u] = sx[base + u];
        py[u] = sy[base + u];
        pz[u] = sz[base + u];
        dist[u] = 1e10f;
    }

    int last = 0;
    float o0x = 0.f, o0y = 0.f, o0z = 0.f;  // centroid index t
    float o1x = 0.f, o1y = 0.f, o1z = 0.f;  // centroid index t + 512

    for (int s = 1; s < NPOINT; ++s) {
        const float cx = sx[last], cy = sy[last], cz = sz[last];
        if (s - 1 == t)       { o0x = cx; o0y = cy; o0z = cz; }
        if (s - 1 == t + 512) { o1x = cx; o1y = cy; o1z = cz; }

        float bv = 0.0f;
#pragma unroll
        for (int u = 0; u < PT; ++u) {
            float dx = __fsub_rn(px[u], cx);
            float dy = __fsub_rn(py[u], cy);
            float dz = __fsub_rn(pz[u], cz);
            float d = __fadd_rn(__fadd_rn(__fmul_rn(dx, dx), __fmul_rn(dy, dy)),
                                __fmul_rn(dz, dz));
            float nd = fminf(dist[u], d);
            dist[u] = nd;
            bv = fmaxf(bv, nd);
        }
        const float wmax = wave64_max_bcast(bv);
        int li = 0;
        if (bv == wmax) {
#pragma unroll
            for (int u = PT - 1; u >= 0; --u)
                if (dist[u] == wmax) li = base + u;  // descending -> smallest
        }
        const unsigned long long m = __ballot(bv == wmax);
        const int fl = __builtin_ctzll(m);
        const int wbi = __builtin_amdgcn_readlane(li, fl);

        if ((t & 63) == 0) {
            redk[s & 1][wv] =
                ((unsigned long long)__float_as_uint(wmax) << 32) |
                (unsigned)(0xFFFFFFFFu - (unsigned)wbi);
        }
        __syncthreads();
        unsigned long long gk = redk[s & 1][0];
#pragma unroll
        for (int w = 1; w < 8; ++w) {
            unsigned long long k2 = redk[s & 1][w];
            if (k2 > gk) gk = k2;
        }
        last = (int)(0xFFFFFFFFu - (unsigned)(gk & 0xFFFFFFFFull));
    }

    {
        const float cx = sx[last], cy = sy[last], cz = sz[last];
        if (t == 511) { o1x = cx; o1y = cy; o1z = cz; }  // 1023 == 511 + 512
    }

    ox[t] = o0x;
    ox[NPOINT + t] = o0y;
    ox[2 * NPOINT + t] = o0z;
    ox[512 + t] = o1x;
    ox[NPOINT + 512 + t] = o1y;
    ox[2 * NPOINT + 512 + t] = o1z;
}

// ---------------------------------------------------------------------------
// layer1A (r15 form): A[b][n][o] = sum_c W0[o][3+c]*pts[b][c][n]; LDS staging
// then coalesced write. Last block computes BN sc/sh constants.
// ---------------------------------------------------------------------------
__global__ __launch_bounds__(256) void layer1_pts_kernel(
    const float* __restrict__ pts, const float* __restrict__ w0,
    float* __restrict__ A,
    const float* __restrict__ b0, const float* __restrict__ g0,
    const float* __restrict__ bt0, const float* __restrict__ rm0,
    const float* __restrict__ rv0,
    const float* __restrict__ b1, const float* __restrict__ g1,
    const float* __restrict__ bt1, const float* __restrict__ rm1,
    const float* __restrict__ rv1,
    const float* __restrict__ b2, const float* __restrict__ g2,
    const float* __restrict__ bt2, const float* __restrict__ rm2,
    const float* __restrict__ rv2, float* __restrict__ bn) {
    const int t = threadIdx.x;
    if (blockIdx.x == BATCH * 64) {
        if (t < 64) {
            float sc = g0[t] * rsqrtf(rv0[t] + BN_EPS);
            bn[t] = sc;
            bn[64 + t] = fmaf(sc, b0[t] - rm0[t], bt0[t]);
        } else if (t < 128) {
            int c = t - 64;
            float sc = g1[c] * rsqrtf(rv1[c] + BN_EPS);
            bn[128 + c] = sc;
            bn[192 + c] = fmaf(sc, b1[c] - rm1[c], bt1[c]);
        } else if (t < 256) {
            int c = t - 128;
            float sc = g2[c] * rsqrtf(rv2[c] + BN_EPS);
            bn[256 + c] = sc;
            bn[384 + c] = fmaf(sc, b2[c] - rm2[c], bt2[c]);
        }
        return;
    }

    __shared__ float sp[64][65];  // [c][n]
    __shared__ float sw[64][65];  // [o][c]
    __shared__ float sA[64][65];  // [n][o] staging for coalesced write
    const int b = blockIdx.x >> 6;
    const int n0 = (blockIdx.x & 63) * 64;
    const int tn = t & 63, tq = t >> 6;  // tq in 0..3
    const float* pb = pts + (size_t)b * DFEAT * NPTS;
#pragma unroll
    for (int i = 0; i < 16; ++i) {
        int c = i * 4 + tq;
        sp[c][tn] = pb[(size_t)c * NPTS + n0 + tn];
    }
#pragma unroll
    for (int i = 0; i < 16; ++i) {
        int o = i * 4 + tq;
        sw[o][tn] = w0[o * CIN + 3 + tn];
    }
    __syncthreads();

#pragma unroll
    for (int i = 0; i < 16; ++i) {
        const int o = tq * 16 + i;
        float a0 = 0.f, a1 = 0.f, a2 = 0.f, a3 = 0.f;
#pragma unroll
        for (int c = 0; c < 64; c += 4) {
            a0 = fmaf(sw[o][c], sp[c][tn], a0);
            a1 = fmaf(sw[o][c + 1], sp[c + 1][tn], a1);
            a2 = fmaf(sw[o][c + 2], sp[c + 2][tn], a2);
            a3 = fmaf(sw[o][c + 3], sp[c + 3][tn], a3);
        }
        sA[tn][o] = (a0 + a1) + (a2 + a3);
    }
    __syncthreads();

    float* Ablk = A + ((size_t)b * NPTS + n0) * DFEAT;
#pragma unroll
    for (int j = 0; j < 16; ++j) {
        const int id = j * 256 + t;
        Ablk[id] = sA[id >> 6][id & 63];
    }
}

// ---------------------------------------------------------------------------
// Ball query (r15 form): one wave per query point, parallel emission via
// prefix popcount. Bit-exact d2, first-32-by-index, pad=first. Zero LDS.
// ---------------------------------------------------------------------------
__global__ __launch_bounds__(256) void ballquery_kernel(const float* __restrict__ xyz,
                                                        const float* __restrict__ dout,
                                                        int* __restrict__ idx) {
    const int wv = threadIdx.x >> 6, lane = threadIdx.x & 63;
    const int sg = blockIdx.x * 4 + wv;  // b*NPOINT + s
    const int b = sg / NPOINT, s = sg % NPOINT;
    const float* xb = xyz + (size_t)b * 3 * NPTS;
    const float* nx = dout + (size_t)b * 3 * NPOINT;
    const float cx = nx[s], cy = nx[NPOINT + s], cz = nx[2 * NPOINT + s];
    int* ob = idx + (size_t)sg * NSAMPLE;
    const float r2 = 0.04f;
    const unsigned long long lmask_lt = ((unsigned long long)1 << lane) - 1;

    int cnt = 0;
    int first = -1;
    for (int tch = 0; tch < NPTS / 64 && cnt < NSAMPLE; ++tch) {
        const int j = tch * 64 + lane;
        float dx = __fsub_rn(cx, xb[j]);
        float dy = __fsub_rn(cy, xb[NPTS + j]);
        float dz = __fsub_rn(cz, xb[2 * NPTS + j]);
        float d2 = __fadd_rn(__fadd_rn(__fmul_rn(dx, dx), __fmul_rn(dy, dy)),
                             __fmul_rn(dz, dz));
        const bool in = (d2 <= r2);
        const unsigned long long mask = __ballot(in);
        if (first < 0 && mask)
            first = tch * 64 + __builtin_ctzll(mask);
        if (in) {
            const int pos = cnt + __builtin_popcountll(mask & lmask_lt);
            if (pos < NSAMPLE) ob[pos] = j;
        }
        cnt += __builtin_popcountll(mask);
    }
    if (lane == 0) {
        for (int r = cnt; r < NSAMPLE; ++r) ob[r] = first;
    }
}

// ---------------------------------------------------------------------------
// Fused group + 3x conv-BN-ReLU + max over nsample. 256 thr (8 s x 32 k).
// CHANGE vs r15: activations x1r/x2r live in REGISTERS (the ylds bounce was
// thread-private — thread t only ever touched column t), removing 64KB LDS,
// 4 barriers, and 512 LDS ops per thread. All indices compile-time constant
// (fully unrolled) so no scratch. Math order identical to r15.
// ---------------------------------------------------------------------------
template <int MODE>
__global__ __launch_bounds__(256) void mlp_kernel(
    const float* __restrict__ xyz, const float* __restrict__ pts,
    const float* __restrict__ A, const int* __restrict__ idx,
    const float* __restrict__ dnew, const float* __restrict__ bn,
    const float* __restrict__ w0, const float* __restrict__ b0,
    const float* __restrict__ g0, const float* __restrict__ bt0,
    const float* __restrict__ rm0, const float* __restrict__ rv0,
    const float* __restrict__ w1, const float* __restrict__ b1,
    const float* __restrict__ g1, const float* __restrict__ bt1,
    const float* __restrict__ rm1, const float* __restrict__ rv1,
    const float* __restrict__ w2, const float* __restrict__ b2,
    const float* __restrict__ g2, const float* __restrict__ bt2,
    const float* __restrict__ rm2, const float* __restrict__ rv2,
    float* __restrict__ outf) {
    const int t = threadIdx.x;
    const int k = t & 31, sl = t >> 5;
    const int b = blockIdx.x >> 7;
    const int s = (blockIdx.x & 127) * 8 + sl;
    const int p = idx[((size_t)(b * NPOINT + s)) * NSAMPLE + k];

    const float* xb = xyz + (size_t)b * 3 * NPTS;
    const float* nx = dnew + (size_t)b * 3 * NPOINT;

    const float gx = xb[p] - nx[s];
    const float gy = xb[NPTS + p] - nx[NPOINT + s];
    const float gz = xb[2 * NPTS + p] - nx[2 * NPOINT + s];

    float x1r[C1];
    if (MODE == 1) {
        const float* Arow = A + ((size_t)b * NPTS + p) * DFEAT;
#pragma unroll
        for (int og = 0; og < C1; og += 4) {
            const float4 av = *(const float4*)(Arow + og);
#pragma unroll
            for (int u = 0; u < 4; ++u) {
                const int o = og + u;
                const float avu = (u == 0) ? av.x : (u == 1) ? av.y
                                 : (u == 2) ? av.z : av.w;
                const float* wr = w0 + o * CIN;
                float acc = fmaf(wr[0], gx,
                            fmaf(wr[1], gy, fmaf(wr[2], gz, avu)));
                float y = fmaf(bn[o], acc, bn[64 + o]);
                x1r[o] = fmaxf(y, 0.f);
            }
        }
    } else {
        float x[CIN];
        x[0] = gx; x[1] = gy; x[2] = gz;
        const float* pb = pts + (size_t)b * DFEAT * NPTS + p;
#pragma unroll
        for (int c = 0; c < DFEAT; ++c) x[3 + c] = pb[(size_t)c * NPTS];
#pragma unroll
        for (int o = 0; o < C1; ++o) {
            const float* wr = w0 + o * CIN;
            float a0 = 0.f, a1 = 0.f, a2 = 0.f, a3 = 0.f;
#pragma unroll
            for (int c = 0; c < 64; c += 4) {
                a0 = fmaf(wr[c], x[c], a0);
                a1 = fmaf(wr[c + 1], x[c + 1], a1);
                a2 = fmaf(wr[c + 2], x[c + 2], a2);
                a3 = fmaf(wr[c + 3], x[c + 3], a3);
            }
            a0 = fmaf(wr[64], x[64], a0);
            a1 = fmaf(wr[65], x[65], a1);
            a2 = fmaf(wr[66], x[66], a2);
            float acc = (a0 + a1) + (a2 + a3);
            float sc = g0[o] * rsqrtf(rv0[o] + BN_EPS);
            float y = fmaf(sc, acc + b0[o] - rm0[o], bt0[o]);
            x1r[o] = fmaxf(y, 0.f);
        }
    }

    // layer 2: 64 -> 64 (register -> register)
    float x2r[C2];
#pragma unroll
    for (int o = 0; o < C2; ++o) {
        const float* wr = w1 + o * C1;
        float a0 = 0.f, a1 = 0.f, a2 = 0.f, a3 = 0.f;
#pragma unroll
        for (int c = 0; c < C1; c += 4) {
            a0 = fmaf(wr[c], x1r[c], a0);
            a1 = fmaf(wr[c + 1], x1r[c + 1], a1);
            a2 = fmaf(wr[c + 2], x1r[c + 2], a2);
            a3 = fmaf(wr[c + 3], x1r[c + 3], a3);
        }
        float acc = (a0 + a1) + (a2 + a3);
        float y;
        if (MODE == 1) {
            y = fmaf(bn[128 + o], acc, bn[192 + o]);
        } else {
            float sc = g1[o] * rsqrtf(rv1[o] + BN_EPS);
            y = fmaf(sc, acc + b1[o] - rm1[o], bt1[o]);
        }
        x2r[o] = fmaxf(y, 0.f);
    }

    // layer 3: 64 -> 128; k-max (DPP) before BN+ReLU, writer lane k==31
    float* ob = outf + (size_t)b * C3 * NPOINT;
    for (int o = 0; o < C3; ++o) {
        const float* wr = w2 + o * C2;
        float a0 = 0.f, a1 = 0.f, a2 = 0.f, a3 = 0.f;
#pragma unroll
        for (int c = 0; c < C2; c += 4) {
            a0 = fmaf(wr[c], x2r[c], a0);
            a1 = fmaf(wr[c + 1], x2r[c + 1], a1);
            a2 = fmaf(wr[c + 2], x2r[c + 2], a2);
            a3 = fmaf(wr[c + 3], x2r[c + 3], a3);
        }
        float acc = (a0 + a1) + (a2 + a3);
        float sc, sh;
        if (MODE == 1) {
            sc = bn[256 + o];
            sh = bn[384 + o];
        } else {
            sc = g2[o] * rsqrtf(rv2[o] + BN_EPS);
            sh = fmaf(sc, b2[o] - rm2[o], bt2[o]);
        }
        float key = (sc >= 0.f) ? acc : -acc;
        float mred = max32_lane31(key);
        if (k == 31) {
            float asel = (sc >= 0.f) ? mred : -mred;
            float y = fmaf(sc, asel, sh);
            ob[(size_t)o * NPOINT + s] = fmaxf(y, 0.f);
        }
    }
}

// ---------------------------------------------------------------------------
extern "C" void kernel_launch(void* const* d_in, const int* in_sizes, int n_in,
                              void* d_out, int out_size, void* d_ws, size_t ws_size,
                              hipStream_t stream) {
    const float* xyz = (const float*)d_in[0];
    const float* pts = (const float*)d_in[1];
    const float* w0 = (const float*)d_in[2];
    const float* b0 = (const float*)d_in[3];
    const float* g0 = (const float*)d_in[4];
    const float* bt0 = (const float*)d_in[5];
    const float* rm0 = (const float*)d_in[6];
    const float* rv0 = (const float*)d_in[7];
    const float* w1 = (const float*)d_in[8];
    const float* b1 = (const float*)d_in[9];
    const float* g1 = (const float*)d_in[10];
    const float* bt1 = (const float*)d_in[11];
    const float* rm1 = (const float*)d_in[12];
    const float* rv1 = (const float*)d_in[13];
    const float* w2 = (const float*)d_in[14];
    const float* b2 = (const float*)d_in[15];
    const float* g2 = (const float*)d_in[16];
    const float* bt2 = (const float*)d_in[17];
    const float* rm2 = (const float*)d_in[18];
    const float* rv2 = (const float*)d_in[19];

    float* out = (float*)d_out;
    float* outf = out + (size_t)BATCH * 3 * NPOINT;

    const size_t idx_bytes = (size_t)BATCH * NPOINT * NSAMPLE * sizeof(int);  // 1 MB
    const size_t idx_pad = (idx_bytes + 255) & ~(size_t)255;
    const size_t A_bytes = (size_t)BATCH * NPTS * DFEAT * sizeof(float);      // 8 MB
    const size_t bn_bytes = 640 * sizeof(float);
    int* idx = (int*)d_ws;
    float* A = (float*)((char*)d_ws + idx_pad);
    float* bn = (float*)((char*)d_ws + idx_pad + A_bytes);
    const bool useA = ws_size >= idx_pad + A_bytes + bn_bytes;

    fps_kernel<<<BATCH, 512, 0, stream>>>(xyz, out);
    if (useA) {
        layer1_pts_kernel<<<BATCH * 64 + 1, 256, 0, stream>>>(
            pts, w0, A, b0, g0, bt0, rm0, rv0, b1, g1, bt1, rm1, rv1,
            b2, g2, bt2, rm2, rv2, bn);
    }
    ballquery_kernel<<<BATCH * NPOINT / 4, 256, 0, stream>>>(xyz, out, idx);
    if (useA) {
        mlp_kernel<1><<<BATCH * NPOINT / 8, 256, 0, stream>>>(
            xyz, pts, A, idx, out, bn, w0, b0, g0, bt0, rm0, rv0, w1, b1, g1,
            bt1, rm1, rv1, w2, b2, g2, bt2, rm2, rv2, outf);
    } else {
        mlp_kernel<0><<<BATCH * NPOINT / 8, 256, 0, stream>>>(
            xyz, pts, A, idx, out, bn, w0, b0, g0, bt0, rm0, rv0, w1, b1, g1,
            bt1, rm1, rv1, w2, b2, g2, bt2, rm2, rv2, outf);
    }
}

// Round 19
// 908.770 us; speedup vs baseline: 1.2173x; 1.0277x over previous
//
#include <hip/hip_runtime.h>
#include <cstdint>
#include <cstddef>

#define NPOINT 1024
#define NSAMPLE 32
#define BATCH 8
#define NPTS 4096
#define DFEAT 64
#define CIN 67
#define C1 64
#define C2 64
#define C3 128
#define BN_EPS 1e-5f

// ---------------------------------------------------------------------------
// DPP helpers. Measured notes: v_pk_*_f32 is NOT double-rate on gfx950
// (r10/r11); pipelined LDS reduce beats serial hazard-chain tails (r6/r16);
// merged dispatches inherit max resource footprint across branches (r14/r17);
// register-MLP is not better than the LDS bounce at this block shape (r18).
// ---------------------------------------------------------------------------
__device__ __forceinline__ float wave64_max_bcast(float v) {
    // values must be >= 0 (bound_ctrl zero-fill loses). Result via lane 63.
    int x;
    x = __builtin_amdgcn_update_dpp(0, __float_as_int(v), 0x111, 0xf, 0xf, true);
    v = fmaxf(v, __int_as_float(x));  // row_shr:1
    x = __builtin_amdgcn_update_dpp(0, __float_as_int(v), 0x112, 0xf, 0xf, true);
    v = fmaxf(v, __int_as_float(x));  // row_shr:2
    x = __builtin_amdgcn_update_dpp(0, __float_as_int(v), 0x114, 0xf, 0xf, true);
    v = fmaxf(v, __int_as_float(x));  // row_shr:4
    x = __builtin_amdgcn_update_dpp(0, __float_as_int(v), 0x118, 0xf, 0xf, true);
    v = fmaxf(v, __int_as_float(x));  // row_shr:8
    x = __builtin_amdgcn_update_dpp(0, __float_as_int(v), 0x142, 0xf, 0xf, true);
    v = fmaxf(v, __int_as_float(x));  // row_bcast:15
    x = __builtin_amdgcn_update_dpp(0, __float_as_int(v), 0x143, 0xf, 0xf, true);
    v = fmaxf(v, __int_as_float(x));  // row_bcast:31
    return __int_as_float(__builtin_amdgcn_readlane(__float_as_int(v), 63));
}

// max over each 32-lane half (negatives safe). Result valid in lanes 31/63.
__device__ __forceinline__ float max32_lane31(float v) {
    int iv = __float_as_int(v), x;
    x = __builtin_amdgcn_update_dpp(iv, iv, 0x111, 0xf, 0xf, false);  // shr1
    v = fmaxf(v, __int_as_float(x)); iv = __float_as_int(v);
    x = __builtin_amdgcn_update_dpp(iv, iv, 0x112, 0xf, 0xf, false);  // shr2
    v = fmaxf(v, __int_as_float(x)); iv = __float_as_int(v);
    x = __builtin_amdgcn_update_dpp(iv, iv, 0x114, 0xf, 0xf, false);  // shr4
    v = fmaxf(v, __int_as_float(x)); iv = __float_as_int(v);
    x = __builtin_amdgcn_update_dpp(iv, iv, 0x118, 0xf, 0xf, false);  // shr8
    v = fmaxf(v, __int_as_float(x)); iv = __float_as_int(v);
    x = __builtin_amdgcn_update_dpp(iv, iv, 0x142, 0xf, 0xf, false);  // bcast15
    v = fmaxf(v, __int_as_float(x));
    return v;
}

// ---------------------------------------------------------------------------
// FPS: byte-identical to r8/r15 champion (644 us). DO NOT TOUCH.
// ---------------------------------------------------------------------------
__global__ __launch_bounds__(512) void fps_kernel(const float* __restrict__ xyz,
                                                  float* __restrict__ dout) {
    const int b = blockIdx.x;
    const float* xb = xyz + (size_t)b * 3 * NPTS;
    float* ox = dout + (size_t)b * 3 * NPOINT;

    __shared__ float sx[NPTS], sy[NPTS], sz[NPTS];
    __shared__ unsigned long long redk[2][8];

    const int t = threadIdx.x;
    const int wv = t >> 6;
    for (int j = t; j < NPTS; j += 512) {
        sx[j] = xb[j];
        sy[j] = xb[NPTS + j];
        sz[j] = xb[2 * NPTS + j];
    }
    __syncthreads();

    constexpr int PT = NPTS / 512;  // 8 points per thread, contiguous
    float px[PT], py[PT], pz[PT], dist[PT];
    const int base = t * PT;
#pragma unroll
    for (int u = 0; u < PT; ++u) {
        px[u] = sx[base + u];
        py[u] = sy[base + u];
        pz[u] = sz[base + u];
        dist[u] = 1e10f;
    }

    int last = 0;
    float o0x = 0.f, o0y = 0.f, o0z = 0.f;  // centroid index t
    float o1x = 0.f, o1y = 0.f, o1z = 0.f;  // centroid index t + 512

    for (int s = 1; s < NPOINT; ++s) {
        const float cx = sx[last], cy = sy[last], cz = sz[last];
        if (s - 1 == t)       { o0x = cx; o0y = cy; o0z = cz; }
        if (s - 1 == t + 512) { o1x = cx; o1y = cy; o1z = cz; }

        float bv = 0.0f;
#pragma unroll
        for (int u = 0; u < PT; ++u) {
            float dx = __fsub_rn(px[u], cx);
            float dy = __fsub_rn(py[u], cy);
            float dz = __fsub_rn(pz[u], cz);
            float d = __fadd_rn(__fadd_rn(__fmul_rn(dx, dx), __fmul_rn(dy, dy)),
                                __fmul_rn(dz, dz));
            float nd = fminf(dist[u], d);
            dist[u] = nd;
            bv = fmaxf(bv, nd);
        }
        const float wmax = wave64_max_bcast(bv);
        int li = 0;
        if (bv == wmax) {
#pragma unroll
            for (int u = PT - 1; u >= 0; --u)
                if (dist[u] == wmax) li = base + u;  // descending -> smallest
        }
        const unsigned long long m = __ballot(bv == wmax);
        const int fl = __builtin_ctzll(m);
        const int wbi = __builtin_amdgcn_readlane(li, fl);

        if ((t & 63) == 0) {
            redk[s & 1][wv] =
                ((unsigned long long)__float_as_uint(wmax) << 32) |
                (unsigned)(0xFFFFFFFFu - (unsigned)wbi);
        }
        __syncthreads();
        unsigned long long gk = redk[s & 1][0];
#pragma unroll
        for (int w = 1; w < 8; ++w) {
            unsigned long long k2 = redk[s & 1][w];
            if (k2 > gk) gk = k2;
        }
        last = (int)(0xFFFFFFFFu - (unsigned)(gk & 0xFFFFFFFFull));
    }

    {
        const float cx = sx[last], cy = sy[last], cz = sz[last];
        if (t == 511) { o1x = cx; o1y = cy; o1z = cz; }  // 1023 == 511 + 512
    }

    ox[t] = o0x;
    ox[NPOINT + t] = o0y;
    ox[2 * NPOINT + t] = o0z;
    ox[512 + t] = o1x;
    ox[NPOINT + 512 + t] = o1y;
    ox[2 * NPOINT + 512 + t] = o1z;
}

// ---------------------------------------------------------------------------
// layer1A: A[b][n][o] = sum_c W0[o][3+c] * pts[b][c][n]; output staged in LDS
// then written coalesced. Last block computes BN sc/sh constants.
// ---------------------------------------------------------------------------
__global__ __launch_bounds__(256) void layer1_pts_kernel(
    const float* __restrict__ pts, const float* __restrict__ w0,
    float* __restrict__ A,
    const float* __restrict__ b0, const float* __restrict__ g0,
    const float* __restrict__ bt0, const float* __restrict__ rm0,
    const float* __restrict__ rv0,
    const float* __restrict__ b1, const float* __restrict__ g1,
    const float* __restrict__ bt1, const float* __restrict__ rm1,
    const float* __restrict__ rv1,
    const float* __restrict__ b2, const float* __restrict__ g2,
    const float* __restrict__ bt2, const float* __restrict__ rm2,
    const float* __restrict__ rv2, float* __restrict__ bn) {
    const int t = threadIdx.x;
    if (blockIdx.x == BATCH * 64) {
        if (t < 64) {
            float sc = g0[t] * rsqrtf(rv0[t] + BN_EPS);
            bn[t] = sc;
            bn[64 + t] = fmaf(sc, b0[t] - rm0[t], bt0[t]);
        } else if (t < 128) {
            int c = t - 64;
            float sc = g1[c] * rsqrtf(rv1[c] + BN_EPS);
            bn[128 + c] = sc;
            bn[192 + c] = fmaf(sc, b1[c] - rm1[c], bt1[c]);
        } else if (t < 256) {
            int c = t - 128;
            float sc = g2[c] * rsqrtf(rv2[c] + BN_EPS);
            bn[256 + c] = sc;
            bn[384 + c] = fmaf(sc, b2[c] - rm2[c], bt2[c]);
        }
        return;
    }

    __shared__ float sp[64][65];  // [c][n]
    __shared__ float sw[64][65];  // [o][c]
    __shared__ float sA[64][65];  // [n][o] staging for coalesced write
    const int b = blockIdx.x >> 6;
    const int n0 = (blockIdx.x & 63) * 64;
    const int tn = t & 63, tq = t >> 6;  // tq in 0..3
    const float* pb = pts + (size_t)b * DFEAT * NPTS;
#pragma unroll
    for (int i = 0; i < 16; ++i) {
        int c = i * 4 + tq;
        sp[c][tn] = pb[(size_t)c * NPTS + n0 + tn];
    }
#pragma unroll
    for (int i = 0; i < 16; ++i) {
        int o = i * 4 + tq;
        sw[o][tn] = w0[o * CIN + 3 + tn];
    }
    __syncthreads();

#pragma unroll
    for (int i = 0; i < 16; ++i) {
        const int o = tq * 16 + i;
        float a0 = 0.f, a1 = 0.f, a2 = 0.f, a3 = 0.f;
#pragma unroll
        for (int c = 0; c < 64; c += 4) {
            a0 = fmaf(sw[o][c], sp[c][tn], a0);
            a1 = fmaf(sw[o][c + 1], sp[c + 1][tn], a1);
            a2 = fmaf(sw[o][c + 2], sp[c + 2][tn], a2);
            a3 = fmaf(sw[o][c + 3], sp[c + 3][tn], a3);
        }
        sA[tn][o] = (a0 + a1) + (a2 + a3);
    }
    __syncthreads();

    // coalesced write: 16384 contiguous floats for this (b, n0) tile
    float* Ablk = A + ((size_t)b * NPTS + n0) * DFEAT;
#pragma unroll
    for (int j = 0; j < 16; ++j) {
        const int id = j * 256 + t;
        Ablk[id] = sA[id >> 6][id & 63];
    }
}

// ---------------------------------------------------------------------------
// Ball query: one wave per query point, parallel emission via prefix
// popcount. Bit-exact d2, first-32-by-index, pad=first. Zero LDS.
// ---------------------------------------------------------------------------
__global__ __launch_bounds__(256) void ballquery_kernel(const float* __restrict__ xyz,
                                                        const float* __restrict__ dout,
                                                        int* __restrict__ idx) {
    const int wv = threadIdx.x >> 6, lane = threadIdx.x & 63;
    const int sg = blockIdx.x * 4 + wv;  // b*NPOINT + s
    const int b = sg / NPOINT, s = sg % NPOINT;
    const float* xb = xyz + (size_t)b * 3 * NPTS;
    const float* nx = dout + (size_t)b * 3 * NPOINT;
    const float cx = nx[s], cy = nx[NPOINT + s], cz = nx[2 * NPOINT + s];
    int* ob = idx + (size_t)sg * NSAMPLE;
    const float r2 = 0.04f;
    const unsigned long long lmask_lt = ((unsigned long long)1 << lane) - 1;

    int cnt = 0;
    int first = -1;
    for (int tch = 0; tch < NPTS / 64 && cnt < NSAMPLE; ++tch) {
        const int j = tch * 64 + lane;
        float dx = __fsub_rn(cx, xb[j]);
        float dy = __fsub_rn(cy, xb[NPTS + j]);
        float dz = __fsub_rn(cz, xb[2 * NPTS + j]);
        float d2 = __fadd_rn(__fadd_rn(__fmul_rn(dx, dx), __fmul_rn(dy, dy)),
                             __fmul_rn(dz, dz));
        const bool in = (d2 <= r2);
        const unsigned long long mask = __ballot(in);
        if (first < 0 && mask)
            first = tch * 64 + __builtin_ctzll(mask);
        if (in) {
            const int pos = cnt + __builtin_popcountll(mask & lmask_lt);
            if (pos < NSAMPLE) ob[pos] = j;
        }
        cnt += __builtin_popcountll(mask);
    }
    if (lane == 0) {
        for (int r = cnt; r < NSAMPLE; ++r) ob[r] = first;
    }
}

// ---------------------------------------------------------------------------
// Fused group + 3x conv-BN-ReLU + max over nsample. 256 thr (8 s x 32 k).
// MODE1: layer 1 = 3 xyz FMAs + precomputed A[p] row; BN via sc/sh table.
// Layer 3: k-max via DPP before BN+ReLU (monotone, sign-safe), writer k==31.
// ---------------------------------------------------------------------------
template <int MODE>
__global__ __launch_bounds__(256) void mlp_kernel(
    const float* __restrict__ xyz, const float* __restrict__ pts,
    const float* __restrict__ A, const int* __restrict__ idx,
    const float* __restrict__ dnew, const float* __restrict__ bn,
    const float* __restrict__ w0, const float* __restrict__ b0,
    const float* __restrict__ g0, const float* __restrict__ bt0,
    const float* __restrict__ rm0, const float* __restrict__ rv0,
    const float* __restrict__ w1, const float* __restrict__ b1,
    const float* __restrict__ g1, const float* __restrict__ bt1,
    const float* __restrict__ rm1, const float* __restrict__ rv1,
    const float* __restrict__ w2, const float* __restrict__ b2,
    const float* __restrict__ g2, const float* __restrict__ bt2,
    const float* __restrict__ rm2, const float* __restrict__ rv2,
    float* __restrict__ outf) {
    __shared__ float ylds[64][256];
    const int t = threadIdx.x;
    const int k = t & 31, sl = t >> 5;
    const int b = blockIdx.x >> 7;
    const int s = (blockIdx.x & 127) * 8 + sl;
    const int p = idx[((size_t)(b * NPOINT + s)) * NSAMPLE + k];

    const float* xb = xyz + (size_t)b * 3 * NPTS;
    const float* nx = dnew + (size_t)b * 3 * NPOINT;

    const float gx = xb[p] - nx[s];
    const float gy = xb[NPTS + p] - nx[NPOINT + s];
    const float gz = xb[2 * NPTS + p] - nx[2 * NPOINT + s];

    if (MODE == 1) {
        const float* Arow = A + ((size_t)b * NPTS + p) * DFEAT;
        for (int og = 0; og < C1; og += 4) {
            const float4 av = *(const float4*)(Arow + og);
#pragma unroll
            for (int u = 0; u < 4; ++u) {
                const int o = og + u;
                const float avu = (u == 0) ? av.x : (u == 1) ? av.y
                                 : (u == 2) ? av.z : av.w;
                const float* wr = w0 + o * CIN;
                float acc = fmaf(wr[0], gx,
                            fmaf(wr[1], gy, fmaf(wr[2], gz, avu)));
                float y = fmaf(bn[o], acc, bn[64 + o]);
                ylds[o][t] = fmaxf(y, 0.f);
            }
        }
    } else {
        float x[CIN];
        x[0] = gx; x[1] = gy; x[2] = gz;
        const float* pb = pts + (size_t)b * DFEAT * NPTS + p;
#pragma unroll
        for (int c = 0; c < DFEAT; ++c) x[3 + c] = pb[(size_t)c * NPTS];
        for (int o = 0; o < C1; ++o) {
            const float* wr = w0 + o * CIN;
            float a0 = 0.f, a1 = 0.f, a2 = 0.f, a3 = 0.f;
#pragma unroll
            for (int c = 0; c < 64; c += 4) {
                a0 = fmaf(wr[c], x[c], a0);
                a1 = fmaf(wr[c + 1], x[c + 1], a1);
                a2 = fmaf(wr[c + 2], x[c + 2], a2);
                a3 = fmaf(wr[c + 3], x[c + 3], a3);
            }
            a0 = fmaf(wr[64], x[64], a0);
            a1 = fmaf(wr[65], x[65], a1);
            a2 = fmaf(wr[66], x[66], a2);
            float acc = (a0 + a1) + (a2 + a3);
            float sc = g0[o] * rsqrtf(rv0[o] + BN_EPS);
            float y = fmaf(sc, acc + b0[o] - rm0[o], bt0[o]);
            ylds[o][t] = fmaxf(y, 0.f);
        }
    }
    __syncthreads();
    float x1[C1];
#pragma unroll
    for (int c = 0; c < C1; ++c) x1[c] = ylds[c][t];
    __syncthreads();

    // layer 2: 64 -> 64
    for (int o = 0; o < C2; ++o) {
        const float* wr = w1 + o * C1;
        float a0 = 0.f, a1 = 0.f, a2 = 0.f, a3 = 0.f;
#pragma unroll
        for (int c = 0; c < C1; c += 4) {
            a0 = fmaf(wr[c], x1[c], a0);
            a1 = fmaf(wr[c + 1], x1[c + 1], a1);
            a2 = fmaf(wr[c + 2], x1[c + 2], a2);
            a3 = fmaf(wr[c + 3], x1[c + 3], a3);
        }
        float acc = (a0 + a1) + (a2 + a3);
        float y;
        if (MODE == 1) {
            y = fmaf(bn[128 + o], acc, bn[192 + o]);
        } else {
            float sc = g1[o] * rsqrtf(rv1[o] + BN_EPS);
            y = fmaf(sc, acc + b1[o] - rm1[o], bt1[o]);
        }
        ylds[o][t] = fmaxf(y, 0.f);
    }
    __syncthreads();
    float x2[C2];
#pragma unroll
    for (int c = 0; c < C2; ++c) x2[c] = ylds[c][t];

    // layer 3: 64 -> 128; k-max (DPP) before BN+ReLU
    float* ob = outf + (size_t)b * C3 * NPOINT;
    for (int o = 0; o < C3; ++o) {
        const float* wr = w2 + o * C2;
        float a0 = 0.f, a1 = 0.f, a2 = 0.f, a3 = 0.f;
#pragma unroll
        for (int c = 0; c < C2; c += 4) {
            a0 = fmaf(wr[c], x2[c], a0);
            a1 = fmaf(wr[c + 1], x2[c + 1], a1);
            a2 = fmaf(wr[c + 2], x2[c + 2], a2);
            a3 = fmaf(wr[c + 3], x2[c + 3], a3);
        }
        float acc = (a0 + a1) + (a2 + a3);
        float sc, sh;
        if (MODE == 1) {
            sc = bn[256 + o];
            sh = bn[384 + o];
        } else {
            sc = g2[o] * rsqrtf(rv2[o] + BN_EPS);
            sh = fmaf(sc, b2[o] - rm2[o], bt2[o]);
        }
        float key = (sc >= 0.f) ? acc : -acc;
        float mred = max32_lane31(key);
        if (k == 31) {
            float asel = (sc >= 0.f) ? mred : -mred;
            float y = fmaf(sc, asel, sh);
            ob[(size_t)o * NPOINT + s] = fmaxf(y, 0.f);
        }
    }
}

// ---------------------------------------------------------------------------
extern "C" void kernel_launch(void* const* d_in, const int* in_sizes, int n_in,
                              void* d_out, int out_size, void* d_ws, size_t ws_size,
                              hipStream_t stream) {
    const float* xyz = (const float*)d_in[0];
    const float* pts = (const float*)d_in[1];
    const float* w0 = (const float*)d_in[2];
    const float* b0 = (const float*)d_in[3];
    const float* g0 = (const float*)d_in[4];
    const float* bt0 = (const float*)d_in[5];
    const float* rm0 = (const float*)d_in[6];
    const float* rv0 = (const float*)d_in[7];
    const float* w1 = (const float*)d_in[8];
    const float* b1 = (const float*)d_in[9];
    const float* g1 = (const float*)d_in[10];
    const float* bt1 = (const float*)d_in[11];
    const float* rm1 = (const float*)d_in[12];
    const float* rv1 = (const float*)d_in[13];
    const float* w2 = (const float*)d_in[14];
    const float* b2 = (const float*)d_in[15];
    const float* g2 = (const float*)d_in[16];
    const float* bt2 = (const float*)d_in[17];
    const float* rm2 = (const float*)d_in[18];
    const float* rv2 = (const float*)d_in[19];

    float* out = (float*)d_out;
    float* outf = out + (size_t)BATCH * 3 * NPOINT;

    const size_t idx_bytes = (size_t)BATCH * NPOINT * NSAMPLE * sizeof(int);  // 1 MB
    const size_t idx_pad = (idx_bytes + 255) & ~(size_t)255;
    const size_t A_bytes = (size_t)BATCH * NPTS * DFEAT * sizeof(float);      // 8 MB
    const size_t bn_bytes = 640 * sizeof(float);
    int* idx = (int*)d_ws;
    float* A = (float*)((char*)d_ws + idx_pad);
    float* bn = (float*)((char*)d_ws + idx_pad + A_bytes);
    const bool useA = ws_size >= idx_pad + A_bytes + bn_bytes;

    fps_kernel<<<BATCH, 512, 0, stream>>>(xyz, out);
    if (useA) {
        layer1_pts_kernel<<<BATCH * 64 + 1, 256, 0, stream>>>(
            pts, w0, A, b0, g0, bt0, rm0, rv0, b1, g1, bt1, rm1, rv1,
            b2, g2, bt2, rm2, rv2, bn);
    }
    ballquery_kernel<<<BATCH * NPOINT / 4, 256, 0, stream>>>(xyz, out, idx);
    if (useA) {
        mlp_kernel<1><<<BATCH * NPOINT / 8, 256, 0, stream>>>(
            xyz, pts, A, idx, out, bn, w0, b0, g0, bt0, rm0, rv0, w1, b1, g1,
            bt1, rm1, rv1, w2, b2, g2, bt2, rm2, rv2, outf);
    } else {
        mlp_kernel<0><<<BATCH * NPOINT / 8, 256, 0, stream>>>(
            xyz, pts, A, idx, out, bn, w0, b0, g0, bt0, rm0, rv0, w1, b1, g1,
            bt1, rm1, rv1, w2, b2, g2, bt2, rm2, rv2, outf);
    }
}